// Round 1
// baseline (393.402 us; speedup 1.0000x reference)
//
#include <hip/hip_runtime.h>
#include <hip/hip_bf16.h>
#include <math.h>

#define Tn   8192
#define Hn   1024
#define En   8
#define DFFn 4096

typedef __attribute__((ext_vector_type(8))) short bf16x8;  // 8 bf16 = 4 VGPRs
typedef __attribute__((ext_vector_type(4))) float f32x4;

// ---------------- gate + x->bf16 conversion ----------------
// One wave per token (grid-stride). Lane l covers h = j*64+l.
__global__ __launch_bounds__(256) void gate_convert(
    const float* __restrict__ x, const float* __restrict__ gW,
    const float* __restrict__ gb, __hip_bfloat16* __restrict__ xbf,
    float* __restrict__ tokw, float* __restrict__ load_sum,
    int* __restrict__ counts)
{
    __shared__ float s_load[En];
    __shared__ int   s_cnt[En];
    const int tid = threadIdx.x;
    if (tid < En) { s_load[tid] = 0.f; s_cnt[tid] = 0; }
    __syncthreads();

    const int lane = tid & 63;
    const int wg   = blockIdx.x * 4 + (tid >> 6);   // 256 waves total

    for (int tok = wg; tok < Tn; tok += 256) {
        const float* xr = x + (size_t)tok * Hn;
        float a0=0.f,a1=0.f,a2=0.f,a3=0.f,a4=0.f,a5=0.f,a6=0.f,a7=0.f;
        #pragma unroll
        for (int j = 0; j < Hn / 64; ++j) {
            int h = j * 64 + lane;
            float xv = xr[h];
            xbf[(size_t)tok * Hn + h] = __float2bfloat16(xv);
            const float4* wp = (const float4*)(gW + (size_t)h * En);
            float4 wa = wp[0], wb = wp[1];
            a0 += xv * wa.x; a1 += xv * wa.y; a2 += xv * wa.z; a3 += xv * wa.w;
            a4 += xv * wb.x; a5 += xv * wb.y; a6 += xv * wb.z; a7 += xv * wb.w;
        }
        float s[8] = {a0,a1,a2,a3,a4,a5,a6,a7};
        #pragma unroll
        for (int e = 0; e < 8; ++e) {
            float v = s[e];
            #pragma unroll
            for (int off = 32; off > 0; off >>= 1) v += __shfl_xor(v, off, 64);
            s[e] = v + gb[e];
        }
        if (lane == 0) {
            #pragma unroll
            for (int e = 0; e < 8; ++e) atomicAdd(&s_load[e], s[e]);
            // top-2 (ties -> lowest index, matching lax.top_k)
            int i1 = 0; float v1 = s[0];
            #pragma unroll
            for (int e = 1; e < 8; ++e) if (s[e] > v1) { v1 = s[e]; i1 = e; }
            int i2 = -1; float v2 = -3.0e38f;
            #pragma unroll
            for (int e = 0; e < 8; ++e) if (e != i1 && s[e] > v2) { v2 = s[e]; i2 = e; }
            atomicAdd(&s_cnt[i1], 1);
            atomicAdd(&s_cnt[i2], 1);
            float e1 = 1.0f;                 // exp(v1 - v1)
            float e2 = expf(v2 - v1);
            float t  = e1 + e2;
            tokw[tok] = e1 / t + e2 / t;     // == softmax(top2).sum()
        }
    }
    __syncthreads();
    if (tid < En) {
        atomicAdd(&load_sum[tid], s_load[tid]);
        atomicAdd(&counts[tid],   s_cnt[tid]);
    }
}

// ---------------- aux loss + counts into output tail ----------------
__global__ void finalize(const float* __restrict__ load_sum,
                         const int* __restrict__ counts,
                         float* __restrict__ out_tail)
{
    if (threadIdx.x == 0) {
        float aux = 0.f;
        #pragma unroll
        for (int e = 0; e < En; ++e) {
            float m = load_sum[e] * (1.0f / (float)Tn);
            aux += m * m;
        }
        out_tail[0] = aux;
        #pragma unroll
        for (int e = 0; e < En; ++e) out_tail[1 + e] = (float)counts[e];
    }
}

// ---------------- W [K][N] fp32 -> Wt [N][K] bf16 ----------------
__global__ __launch_bounds__(256) void transpose_cast(
    const float* __restrict__ src, __hip_bfloat16* __restrict__ dst,
    int Kd, int Nd)
{
    __shared__ float tile[32][33];
    const int n0 = blockIdx.x * 32, k0 = blockIdx.y * 32;
    const int tx = threadIdx.x & 31, ty = threadIdx.x >> 5;  // ty: 0..7
    #pragma unroll
    for (int r = 0; r < 32; r += 8)
        tile[ty + r][tx] = src[(size_t)(k0 + ty + r) * Nd + n0 + tx];
    __syncthreads();
    #pragma unroll
    for (int r = 0; r < 32; r += 8)
        dst[(size_t)(n0 + ty + r) * Kd + k0 + tx] = __float2bfloat16(tile[tx][ty + r]);
}

// ---------------- m97-style bf16 GEMM, C = epilogue(A @ Bt^T + bias) ------
// A  : [M][K] bf16 row-major
// Bt : [N][K] bf16 row-major (B transposed)
// EPI==0: C = bf16( gelu_exact(v) )   (hdd)
// EPI==1: C = fp32( v * tokw[row] )   (final output)
template<int EPI>
__global__ __launch_bounds__(256) void gemm_bt(
    const __hip_bfloat16* __restrict__ A,
    const __hip_bfloat16* __restrict__ Bt,
    const float* __restrict__ bias,
    const float* __restrict__ tokw,
    void* __restrict__ C, int M, int N, int K)
{
    __shared__ __hip_bfloat16 sA[128 * 32];   // no padding: global_load_lds layout
    __shared__ __hip_bfloat16 sB[128 * 32];

    const int tid  = threadIdx.x;
    const int lane = tid & 63;
    const int wv   = tid >> 6;
    const int wm   = (wv >> 1) * 64;          // wave row offset in tile
    const int wn   = (wv & 1) * 64;           // wave col offset in tile
    const int m0   = blockIdx.y * 128, n0 = blockIdx.x * 128;

    f32x4 acc[4][4];
    const f32x4 zero = {0.f, 0.f, 0.f, 0.f};
    #pragma unroll
    for (int i = 0; i < 4; ++i)
        #pragma unroll
        for (int j = 0; j < 4; ++j) acc[i][j] = zero;

    // staging coords: thread t covers 16B chunk (row = t>>2, kcol = (t&3)*8);
    // second pass covers rows +64 at LDS offset +2048 elems.
    const int r0 = tid >> 2;
    const int kc = (tid & 3) * 8;
    const __hip_bfloat16* gA = A  + (size_t)(m0 + r0) * K + kc;
    const __hip_bfloat16* gB = Bt + (size_t)(n0 + r0) * K + kc;
    const size_t half = (size_t)64 * K;

    const int fr = lane & 15;                 // fragment row/col within 16
    const int fk = (lane >> 4) * 8;           // k-offset of 8-elem group

    for (int k0 = 0; k0 < K; k0 += 32) {
        __syncthreads();
        __builtin_amdgcn_global_load_lds(
            (const __attribute__((address_space(1))) void*)(gA + k0),
            (__attribute__((address_space(3))) void*)(sA + tid * 8), 16, 0, 0);
        __builtin_amdgcn_global_load_lds(
            (const __attribute__((address_space(1))) void*)(gA + half + k0),
            (__attribute__((address_space(3))) void*)(sA + 2048 + tid * 8), 16, 0, 0);
        __builtin_amdgcn_global_load_lds(
            (const __attribute__((address_space(1))) void*)(gB + k0),
            (__attribute__((address_space(3))) void*)(sB + tid * 8), 16, 0, 0);
        __builtin_amdgcn_global_load_lds(
            (const __attribute__((address_space(1))) void*)(gB + half + k0),
            (__attribute__((address_space(3))) void*)(sB + 2048 + tid * 8), 16, 0, 0);
        __syncthreads();

        bf16x8 af[4], bfr[4];
        #pragma unroll
        for (int mi = 0; mi < 4; ++mi)
            af[mi] = *(const bf16x8*)(sA + (wm + mi * 16 + fr) * 32 + fk);
        #pragma unroll
        for (int ni = 0; ni < 4; ++ni)
            bfr[ni] = *(const bf16x8*)(sB + (wn + ni * 16 + fr) * 32 + fk);
        #pragma unroll
        for (int mi = 0; mi < 4; ++mi)
            #pragma unroll
            for (int ni = 0; ni < 4; ++ni)
                acc[mi][ni] = __builtin_amdgcn_mfma_f32_16x16x32_bf16(
                    af[mi], bfr[ni], acc[mi][ni], 0, 0, 0);
    }

    // epilogue: C/D layout col = lane&15, row = (lane>>4)*4 + reg
    #pragma unroll
    for (int mi = 0; mi < 4; ++mi) {
        #pragma unroll
        for (int ni = 0; ni < 4; ++ni) {
            const int col   = n0 + wn + ni * 16 + (lane & 15);
            const int rbase = m0 + wm + mi * 16 + (lane >> 4) * 4;
            const float bv  = bias[col];
            #pragma unroll
            for (int i = 0; i < 4; ++i) {
                const int row = rbase + i;
                float v = acc[mi][ni][i] + bv;
                if (EPI == 0) {
                    float g = 0.5f * v * (1.0f + erff(v * 0.70710678118654752f));
                    ((__hip_bfloat16*)C)[(size_t)row * N + col] = __float2bfloat16(g);
                } else {
                    ((float*)C)[(size_t)row * N + col] = v * tokw[row];
                }
            }
        }
    }
}

extern "C" void kernel_launch(void* const* d_in, const int* in_sizes, int n_in,
                              void* d_out, int out_size, void* d_ws, size_t ws_size,
                              hipStream_t stream)
{
    const float* x  = (const float*)d_in[0];
    const float* gW = (const float*)d_in[1];
    const float* gb = (const float*)d_in[2];
    const float* W1 = (const float*)d_in[3];
    const float* b1 = (const float*)d_in[4];
    const float* W2 = (const float*)d_in[5];
    const float* b2 = (const float*)d_in[6];
    float* out = (float*)d_out;

    char* ws = (char*)d_ws;
    __hip_bfloat16* xbf = (__hip_bfloat16*)ws;  ws += (size_t)Tn * Hn * 2;     // 16 MB
    __hip_bfloat16* W1t = (__hip_bfloat16*)ws;  ws += (size_t)Hn * DFFn * 2;   //  8 MB
    __hip_bfloat16* W2t = (__hip_bfloat16*)ws;  ws += (size_t)Hn * DFFn * 2;   //  8 MB
    __hip_bfloat16* hdd = (__hip_bfloat16*)ws;  ws += (size_t)Tn * DFFn * 2;   // 64 MB
    float* tokw     = (float*)ws;               ws += (size_t)Tn * 4;          // 32 KB
    float* load_sum = (float*)ws;               ws += En * 4;
    int*   counts   = (int*)ws;                 ws += En * 4;

    hipMemsetAsync(load_sum, 0, En * 4 * 2, stream);   // zero load_sum + counts

    transpose_cast<<<dim3(DFFn / 32, Hn / 32), 256, 0, stream>>>(W1, W1t, Hn, DFFn);
    transpose_cast<<<dim3(Hn / 32, DFFn / 32), 256, 0, stream>>>(W2, W2t, DFFn, Hn);
    gate_convert<<<64, 256, 0, stream>>>(x, gW, gb, xbf, tokw, load_sum, counts);
    finalize<<<1, 64, 0, stream>>>(load_sum, counts, out + (size_t)Tn * Hn);

    // hdd = gelu(x @ W1 + b1)            [8192 x 4096]
    gemm_bt<0><<<dim3(DFFn / 128, Tn / 128), 256, 0, stream>>>(
        xbf, W1t, b1, nullptr, hdd, Tn, DFFn, Hn);
    // out = (hdd @ W2 + b2) * tokw[row]  [8192 x 1024]
    gemm_bt<1><<<dim3(Hn / 128, Tn / 128), 256, 0, stream>>>(
        hdd, W2t, b2, tokw, out, Tn, Hn, DFFn);
}